// Round 1
// baseline (866.250 us; speedup 1.0000x reference)
//
#include <hip/hip_runtime.h>
#include <hip/hip_bf16.h>

// MiniMax MoE top-2, MI355X. T=2048 tokens, H=2048, F=4096, E=8.
// Structure: router (fp32) -> expert-major pair compaction -> grouped GEMM1
// (gate+up, silu*mul, bf16 MFMA) -> grouped GEMM2 (down) -> weighted atomicAdd.

#define T_TOK 2048
#define H_DIM 2048
#define F_DIM 4096
#define E_NUM 8
#define NPAIR (T_TOK * 2)

typedef __attribute__((ext_vector_type(8))) short short8;
typedef __attribute__((ext_vector_type(4))) float f32x4;

__device__ __forceinline__ unsigned short f2bf(float f) {
    unsigned u = __builtin_bit_cast(unsigned, f);
    u = (u + 0x7FFFu + ((u >> 16) & 1u)) >> 16;   // RNE
    return (unsigned short)u;
}

// ---- x fp32 -> bf16 ----------------------------------------------------
__global__ void k_cvt_x(const float* __restrict__ x, ushort* __restrict__ xb) {
    int i = blockIdx.x * blockDim.x + threadIdx.x;     // one uint4 (8 bf16) per thread
    const float4* p = (const float4*)x + (size_t)i * 2;
    float4 a = p[0], b = p[1];
    uint4 o;
    o.x = f2bf(a.x) | ((unsigned)f2bf(a.y) << 16);
    o.y = f2bf(a.z) | ((unsigned)f2bf(a.w) << 16);
    o.z = f2bf(b.x) | ((unsigned)f2bf(b.y) << 16);
    o.w = f2bf(b.z) | ((unsigned)f2bf(b.w) << 16);
    ((uint4*)xb)[i] = o;
}

// ---- router: fp32 logits, top-2, renormalized weights ------------------
__global__ void k_router(const float* __restrict__ x, const float* __restrict__ gw,
                         int2* __restrict__ eidx, float2* __restrict__ ew,
                         int* __restrict__ cnt) {
    int t = blockIdx.x * 4 + (threadIdx.x >> 6);       // 4 tokens/block, 1 wave each
    int lane = threadIdx.x & 63;
    const float* xr = x + (size_t)t * H_DIM;
    float l[E_NUM];
    #pragma unroll
    for (int e = 0; e < E_NUM; e++) {
        const float* wr = gw + (size_t)e * H_DIM;
        float acc = 0.f;
        for (int i = lane; i < H_DIM; i += 64) acc += xr[i] * wr[i];
        #pragma unroll
        for (int o = 32; o; o >>= 1) acc += __shfl_xor(acc, o);
        l[e] = acc;
    }
    if (lane == 0) {
        int e0 = 0;
        #pragma unroll
        for (int e = 1; e < E_NUM; e++) if (l[e] > l[e0]) e0 = e;   // first-max wins ties
        int e1 = -1;
        #pragma unroll
        for (int e = 0; e < E_NUM; e++) {
            if (e == e0) continue;
            if (e1 < 0 || l[e] > l[e1]) e1 = e;
        }
        // renormalized top-2 softmax == softmax over the two logits
        float s1 = expf(l[e1] - l[e0]);
        float w0 = 1.f / (1.f + s1);
        float w1 = s1 * w0;
        eidx[t] = make_int2(e0, e1);
        ew[t]   = make_float2(w0, w1);
        atomicAdd(&cnt[e0], 1);
        atomicAdd(&cnt[e1], 1);
    }
}

// ---- prefix over 8 experts --------------------------------------------
__global__ void k_off(const int* __restrict__ cnt, int* __restrict__ off,
                      int* __restrict__ cnt2) {
    if (threadIdx.x == 0) {
        int s = 0;
        for (int e = 0; e < E_NUM; e++) { off[e] = s; s += cnt[e]; cnt2[e] = 0; }
        off[E_NUM] = s;   // == NPAIR
    }
}

// ---- scatter (token, weight) pairs expert-major ------------------------
__global__ void k_fill(const int2* __restrict__ eidx, const float2* __restrict__ ew,
                       const int* __restrict__ off, int* __restrict__ cnt2,
                       int* __restrict__ ptok, float* __restrict__ pw) {
    int t = blockIdx.x * blockDim.x + threadIdx.x;
    if (t >= T_TOK) return;
    int2 e = eidx[t];
    float2 w = ew[t];
    int p0 = off[e.x] + atomicAdd(&cnt2[e.x], 1);
    ptok[p0] = t; pw[p0] = w.x;
    int p1 = off[e.y] + atomicAdd(&cnt2[e.y], 1);
    ptok[p1] = t; pw[p1] = w.y;
}

// ---- grouped GEMM1: h = silu(X Wg^T) * (X Wu^T), per expert ------------
// Tile 64(M pairs) x 64(N f-cols), BK=32, 4 waves (each wave: 16M x 64N).
__global__ __launch_bounds__(256) void k_gemm1(
        const ushort* __restrict__ xb, const float* __restrict__ wg,
        const float* __restrict__ wu, const int* __restrict__ ptok,
        const int* __restrict__ off, ushort* __restrict__ hbuf) {
    __shared__ __align__(16) ushort As[64][40];   // +8 pad: banks spread
    __shared__ __align__(16) ushort Bgs[64][40];
    __shared__ __align__(16) ushort Bus[64][40];

    int e = blockIdx.y >> 6, mt = blockIdx.y & 63;
    int base = off[e], ne = off[e + 1] - base;
    int row0 = mt * 64;
    if (row0 >= ne) return;

    int tid = threadIdx.x;
    int srow = tid >> 2, kg = tid & 3;            // staging: row, 8-elem k-group
    bool valid = (row0 + srow) < ne;
    int tok = valid ? ptok[base + row0 + srow] : 0;
    int nb = blockIdx.x * 64;
    int wv = tid >> 6, lane = tid & 63, lr = lane & 15, lk = lane >> 4;

    f32x4 accg[4] = {}; f32x4 accu[4] = {};

    const ushort* xrow  = xb + (size_t)tok * H_DIM + kg * 8;
    const float*  wgrow = wg + ((size_t)e * F_DIM + nb + srow) * H_DIM + kg * 8;
    const float*  wurow = wu + ((size_t)e * F_DIM + nb + srow) * H_DIM + kg * 8;

    for (int kb = 0; kb < H_DIM; kb += 32) {
        __syncthreads();
        uint4 av = valid ? *(const uint4*)(xrow + kb) : make_uint4(0, 0, 0, 0);
        *(uint4*)(&As[srow][kg * 8]) = av;

        float4 g0 = *(const float4*)(wgrow + kb);
        float4 g1 = *(const float4*)(wgrow + kb + 4);
        uint4 bg;
        bg.x = f2bf(g0.x) | ((unsigned)f2bf(g0.y) << 16);
        bg.y = f2bf(g0.z) | ((unsigned)f2bf(g0.w) << 16);
        bg.z = f2bf(g1.x) | ((unsigned)f2bf(g1.y) << 16);
        bg.w = f2bf(g1.z) | ((unsigned)f2bf(g1.w) << 16);
        *(uint4*)(&Bgs[srow][kg * 8]) = bg;

        float4 u0 = *(const float4*)(wurow + kb);
        float4 u1 = *(const float4*)(wurow + kb + 4);
        uint4 bu;
        bu.x = f2bf(u0.x) | ((unsigned)f2bf(u0.y) << 16);
        bu.y = f2bf(u0.z) | ((unsigned)f2bf(u0.w) << 16);
        bu.z = f2bf(u1.x) | ((unsigned)f2bf(u1.y) << 16);
        bu.w = f2bf(u1.z) | ((unsigned)f2bf(u1.w) << 16);
        *(uint4*)(&Bus[srow][kg * 8]) = bu;
        __syncthreads();

        short8 af = *(const short8*)(&As[wv * 16 + lr][lk * 8]);
        #pragma unroll
        for (int s = 0; s < 4; s++) {
            short8 b8g = *(const short8*)(&Bgs[s * 16 + lr][lk * 8]);
            accg[s] = __builtin_amdgcn_mfma_f32_16x16x32_bf16(af, b8g, accg[s], 0, 0, 0);
            short8 b8u = *(const short8*)(&Bus[s * 16 + lr][lk * 8]);
            accu[s] = __builtin_amdgcn_mfma_f32_16x16x32_bf16(af, b8u, accu[s], 0, 0, 0);
        }
    }

    // epilogue: silu(g)*u -> bf16 h row (C/D map: row=(lane>>4)*4+r, col=lane&15)
    #pragma unroll
    for (int s = 0; s < 4; s++) {
        #pragma unroll
        for (int r = 0; r < 4; r++) {
            int orow = wv * 16 + lk * 4 + r;
            if (row0 + orow < ne) {
                float g = accg[s][r], u = accu[s][r];
                float hv = g / (1.f + expf(-g)) * u;
                hbuf[(size_t)(base + row0 + orow) * F_DIM + nb + s * 16 + lr] = f2bf(hv);
            }
        }
    }
}

// ---- grouped GEMM2: y = h Wd^T, scaled atomicAdd into out --------------
__global__ __launch_bounds__(256) void k_gemm2(
        const ushort* __restrict__ hbuf, const float* __restrict__ wd,
        const int* __restrict__ ptok, const float* __restrict__ pw,
        const int* __restrict__ off, float* __restrict__ out) {
    __shared__ __align__(16) ushort As[64][40];
    __shared__ __align__(16) ushort Bs[64][40];

    int e = blockIdx.y >> 6, mt = blockIdx.y & 63;
    int base = off[e], ne = off[e + 1] - base;
    int row0 = mt * 64;
    if (row0 >= ne) return;

    int tid = threadIdx.x;
    int srow = tid >> 2, kg = tid & 3;
    bool valid = (row0 + srow) < ne;
    int nb = blockIdx.x * 64;
    int wv = tid >> 6, lane = tid & 63, lr = lane & 15, lk = lane >> 4;

    f32x4 acc[4] = {};
    const ushort* hrow  = hbuf + (size_t)(base + row0 + srow) * F_DIM + kg * 8;
    const float*  wdrow = wd + ((size_t)e * H_DIM + nb + srow) * F_DIM + kg * 8;

    for (int kb = 0; kb < F_DIM; kb += 32) {
        __syncthreads();
        uint4 av = valid ? *(const uint4*)(hrow + kb) : make_uint4(0, 0, 0, 0);
        *(uint4*)(&As[srow][kg * 8]) = av;

        float4 b0 = *(const float4*)(wdrow + kb);
        float4 b1 = *(const float4*)(wdrow + kb + 4);
        uint4 bb;
        bb.x = f2bf(b0.x) | ((unsigned)f2bf(b0.y) << 16);
        bb.y = f2bf(b0.z) | ((unsigned)f2bf(b0.w) << 16);
        bb.z = f2bf(b1.x) | ((unsigned)f2bf(b1.y) << 16);
        bb.w = f2bf(b1.z) | ((unsigned)f2bf(b1.w) << 16);
        *(uint4*)(&Bs[srow][kg * 8]) = bb;
        __syncthreads();

        short8 af = *(const short8*)(&As[wv * 16 + lr][lk * 8]);
        #pragma unroll
        for (int s = 0; s < 4; s++) {
            short8 b8 = *(const short8*)(&Bs[s * 16 + lr][lk * 8]);
            acc[s] = __builtin_amdgcn_mfma_f32_16x16x32_bf16(af, b8, acc[s], 0, 0, 0);
        }
    }

    #pragma unroll
    for (int s = 0; s < 4; s++) {
        #pragma unroll
        for (int r = 0; r < 4; r++) {
            int orow = wv * 16 + lk * 4 + r;
            if (row0 + orow < ne) {
                int p = base + row0 + orow;
                int tk = ptok[p];
                float w = pw[p];
                atomicAdd(&out[(size_t)tk * H_DIM + nb + s * 16 + lr], w * acc[s][r]);
            }
        }
    }
}

extern "C" void kernel_launch(void* const* d_in, const int* in_sizes, int n_in,
                              void* d_out, int out_size, void* d_ws, size_t ws_size,
                              hipStream_t stream) {
    const float* x  = (const float*)d_in[0];
    const float* gw = (const float*)d_in[1];
    const float* wg = (const float*)d_in[2];
    const float* wu = (const float*)d_in[3];
    const float* wd = (const float*)d_in[4];
    float* out = (float*)d_out;

    char* ws = (char*)d_ws;
    size_t o = 0;
    ushort* xb   = (ushort*)(ws + o); o += (size_t)T_TOK * H_DIM * 2;   // 8 MB
    ushort* hbuf = (ushort*)(ws + o); o += (size_t)NPAIR * F_DIM * 2;   // 32 MB
    int*    ptok = (int*)   (ws + o); o += NPAIR * 4;
    float*  pw   = (float*) (ws + o); o += NPAIR * 4;
    int2*   eidx = (int2*)  (ws + o); o += T_TOK * 8;
    float2* ew   = (float2*)(ws + o); o += T_TOK * 8;
    int*    cnt  = (int*)   (ws + o); o += 256;
    int*    cnt2 = (int*)   (ws + o); o += 256;
    int*    off  = (int*)   (ws + o); o += 256;

    hipMemsetAsync(cnt, 0, 256, stream);
    hipMemsetAsync(out, 0, (size_t)out_size * 4, stream);

    k_cvt_x <<<T_TOK * H_DIM / 8 / 256, 256, 0, stream>>>(x, xb);
    k_router<<<T_TOK / 4, 256, 0, stream>>>(x, gw, eidx, ew, cnt);
    k_off   <<<1, 64, 0, stream>>>(cnt, off, cnt2);
    k_fill  <<<T_TOK / 256, 256, 0, stream>>>(eidx, ew, off, cnt2, ptok, pw);

    dim3 g1(F_DIM / 64, E_NUM * 64);
    k_gemm1<<<g1, 256, 0, stream>>>(xb, wg, wu, ptok, off, hbuf);
    dim3 g2(H_DIM / 64, E_NUM * 64);
    k_gemm2<<<g2, 256, 0, stream>>>(hbuf, wd, ptok, pw, off, out);
}